// Round 14
// baseline (180.827 us; speedup 1.0000x reference)
//
#include <hip/hip_runtime.h>
#include <stdint.h>

#define D 128

typedef __bf16 bf16x8 __attribute__((ext_vector_type(8)));
typedef float f32x4  __attribute__((ext_vector_type(4)));

__device__ __forceinline__ float b2f(ushort u) {
    uint x = ((uint)u) << 16;
    return __builtin_bit_cast(float, x);
}
__device__ __forceinline__ ushort f2b(float f) {   // round-to-nearest-even
    uint u = __builtin_bit_cast(uint, f);
    u += 0x7FFFu + ((u >> 16) & 1u);
    return (ushort)(u >> 16);
}
// swizzle: XOR low-3 bits of the 16B slot with the 512B pair-row index
__device__ __forceinline__ int swz(int b) { return b ^ (((b >> 9) & 7) << 4); }

// ---------------------------------------------------------------------------
// prep: blocks 0..191 pack weights (fragment-major bf16); block 192 builds
// the rank-interleaved item table: tab[2c]=rank c, tab[2c+1]=rank 511-c,
// so any 2-block grouping a CU receives sums to ~T/256 rows.
// ---------------------------------------------------------------------------
__global__ void __launch_bounds__(512) prep_kernel(
    const float* __restrict__ W1, const float* __restrict__ W2,
    const int* __restrict__ limits,
    ushort* __restrict__ W1p, ushort* __restrict__ W2p,
    int2* __restrict__ itemTab)
{
    if (blockIdx.x < 192) {
        int g = blockIdx.x * 512 + threadIdx.x;
        if (g < 65536) {
            int t = g & 7, l = (g >> 3) & 63, nt = (g >> 9) & 15, kk = g >> 13;
            int krow = kk * 32 + (l >> 4) * 8 + t;
            int col  = nt * 16 + (l & 15);
            W1p[g] = f2b(W1[krow * 256 + col]);
        } else {
            int g2 = g - 65536;
            int t = g2 & 7, l = (g2 >> 3) & 63, nt = (g2 >> 9) & 7, kk = g2 >> 12;
            int krow = kk * 32 + (l >> 4) * 8 + t;
            int col  = nt * 16 + (l & 15);
            W2p[g2] = f2b(W2[krow * 128 + col]);
        }
        return;
    }
    // ---- rank items by descending L; interleave big/small
    __shared__ ushort Ls[512];
    __shared__ ushort rnkIdx[512];
    const int tid = threadIdx.x;
    int Lm = min(max(limits[tid + 1] - limits[tid], 1), 256);
    Ls[tid] = (ushort)Lm;
    __syncthreads();
    int rank = 0;
    for (int j = 0; j < 512; ++j) {
        int Lj = Ls[j];
        rank += (Lj > Lm) || (Lj == Lm && j < tid);
    }
    rnkIdx[rank] = (ushort)tid;
    __syncthreads();
    if (tid < 256) {
        int iA = rnkIdx[tid], iB = rnkIdx[511 - tid];
        itemTab[2 * tid]     = int2{ iA | (((int)Ls[iA]) << 16), limits[iA] };
        itemTab[2 * tid + 1] = int2{ iB | (((int)Ls[iB]) << 16), limits[iB] };
    }
}

// ---------------------------------------------------------------------------
// Level body, compile-time NMF (<=8 fragments = <=128 pairs; G==1).
// GEMM1: multipass FPP=2, W1 in regs. GEMM2: operand-swapped N-split-8,
// W2 in regs. LN: 2-shfl partials -> pbuf -> cross-wave combine.
// ---------------------------------------------------------------------------
template<int NMF>
__device__ __forceinline__ void level_body(
    char* __restrict__ Xw, const unsigned* __restrict__ sk,
    const uint4 (&w1r)[8][2], const uint4 (&w2r)[8],
    const float (&bb1)[2][4], const float (&bb2v)[4],
    const float (&lwv)[4], const float (&lbv)[4],
    float2* __restrict__ pbuf, int cpS,
    int tid, int lane, int w)
{
    constexpr int FPP   = (NMF >= 2) ? 2 : 1;
    constexpr int NPASS = NMF / FPP;

    // ---- GEMM1 (swapped, N-split-8), FPP fragments per pass ----
    #pragma unroll
    for (int p = 0; p < NPASS; ++p) {
        unsigned pa[FPP];
        #pragma unroll
        for (int mf = 0; mf < FPP; ++mf) pa[mf] = sk[(p * FPP + mf) * 16 + (lane & 15)];

        f32x4 acc1[2][FPP];
        #pragma unroll
        for (int n = 0; n < 2; ++n)
            #pragma unroll
            for (int mf = 0; mf < FPP; ++mf) acc1[n][mf] = f32x4{0.f, 0.f, 0.f, 0.f};

        #pragma unroll
        for (int kk = 0; kk < 8; ++kk) {
            uint4 xv[FPP];
            #pragma unroll
            for (int mf = 0; mf < FPP; ++mf) {
                int prow = (int)(pa[mf] & 0xFFFFu);
                xv[mf] = *(const uint4*)(Xw + (prow * 512 + ((kk * 64 + (lane >> 4) * 16) ^ ((prow & 7) << 4))));
            }
            #pragma unroll
            for (int n = 0; n < 2; ++n) {
                bf16x8 af = __builtin_bit_cast(bf16x8, w1r[kk][n]);
                #pragma unroll
                for (int mf = 0; mf < FPP; ++mf)
                    acc1[n][mf] = __builtin_amdgcn_mfma_f32_16x16x32_bf16(
                        af, __builtin_bit_cast(bf16x8, xv[mf]), acc1[n][mf], 0, 0, 0);
            }
        }
        __syncthreads();   // all waves' X reads for this pass done

        // H write-back for this pass (lane holds 4 consecutive H cols)
        #pragma unroll
        for (int mf = 0; mf < FPP; ++mf) {
            if ((pa[mf] >> 16) != 0xFFFFu) {
                int prow = (int)(pa[mf] & 0xFFFFu);
                int rbase = prow * 512, sm = (prow & 7) << 4;
                #pragma unroll
                for (int n = 0; n < 2; ++n) {
                    float h0 = fmaxf(acc1[n][mf][0] + bb1[n][0], 0.f);
                    float h1 = fmaxf(acc1[n][mf][1] + bb1[n][1], 0.f);
                    float h2 = fmaxf(acc1[n][mf][2] + bb1[n][2], 0.f);
                    float h3 = fmaxf(acc1[n][mf][3] + bb1[n][3], 0.f);
                    uint2 pk;
                    pk.x = (uint)f2b(h0) | ((uint)f2b(h1) << 16);
                    pk.y = (uint)f2b(h2) | ((uint)f2b(h3) << 16);
                    *(uint2*)(Xw + (rbase + ((64 * w + 32 * n + 8 * (lane >> 4)) ^ sm))) = pk;
                }
            }
        }
    }
    __syncthreads();   // final pass's H visible

    // ---- GEMM2 swapped: acc2[mf] = Y^T fragment for wave's 16 Y-cols ----
    unsigned pa2[NMF];
    #pragma unroll
    for (int mf = 0; mf < NMF; ++mf) pa2[mf] = sk[mf * 16 + (lane & 15)];

    f32x4 acc2[NMF];
    #pragma unroll
    for (int mf = 0; mf < NMF; ++mf) acc2[mf] = f32x4{0.f, 0.f, 0.f, 0.f};

    #pragma unroll
    for (int kk = 0; kk < 8; ++kk) {
        bf16x8 af = __builtin_bit_cast(bf16x8, w2r[kk]);
        #pragma unroll
        for (int mf = 0; mf < NMF; ++mf) {
            int prow = (int)(pa2[mf] & 0xFFFFu);
            uint4 hv = *(const uint4*)(Xw + (prow * 512 + ((kk * 64 + (lane >> 4) * 16) ^ ((prow & 7) << 4))));
            acc2[mf] = __builtin_amdgcn_mfma_f32_16x16x32_bf16(
                af, __builtin_bit_cast(bf16x8, hv), acc2[mf], 0, 0, 0);
        }
    }

    // bias + 16-col LN partials -> pbuf[w][pair]
    #pragma unroll
    for (int mf = 0; mf < NMF; ++mf) {
        float s1 = 0.f, s2 = 0.f;
        #pragma unroll
        for (int i = 0; i < 4; ++i) {
            float v = acc2[mf][i] + bb2v[i];
            acc2[mf][i] = v; s1 += v; s2 += v * v;
        }
        s1 += __shfl_xor(s1, 16, 64); s2 += __shfl_xor(s2, 16, 64);
        s1 += __shfl_xor(s1, 32, 64); s2 += __shfl_xor(s2, 32, 64);
        if ((lane >> 4) == 0)
            pbuf[w * 128 + mf * 16 + (lane & 15)] = float2{s1, s2};
    }
    __syncthreads();   // H reads done + partials visible

    // combine partials, normalize, write Y (4 consecutive cols per lane)
    #pragma unroll
    for (int mf = 0; mf < NMF; ++mf) {
        int yd = (int)(pa2[mf] >> 16);
        if (yd != 0xFFFF) {
            int p = mf * 16 + (lane & 15);
            float S1 = 0.f, S2 = 0.f;
            #pragma unroll
            for (int ww = 0; ww < 8; ++ww) {
                float2 o = pbuf[ww * 128 + p];
                S1 += o.x; S2 += o.y;
            }
            float mu = S1 * (1.f / 128.f);
            float var = S2 * (1.f / 128.f) - mu * mu;
            float rs = rsqrtf(var + 1e-5f);
            float v0 = (acc2[mf][0] - mu) * rs * lwv[0] + lbv[0];
            float v1 = (acc2[mf][1] - mu) * rs * lwv[1] + lbv[1];
            float v2 = (acc2[mf][2] - mu) * rs * lwv[2] + lbv[2];
            float v3 = (acc2[mf][3] - mu) * rs * lwv[3] + lbv[3];
            uint2 pk;
            pk.x = (uint)f2b(v0) | ((uint)f2b(v1) << 16);
            pk.y = (uint)f2b(v2) | ((uint)f2b(v3) << 16);
            *(uint2*)(Xw + swz(yd * 256 + (16 * w + 4 * (lane >> 4)) * 2)) = pk;
        }
    }
    // leftover row: copy row (l-1) -> row 0 (odd level); 16 chunks, tid<16
    if (cpS != 0xFFFF && tid < 16) {
        uint4 v = *(const uint4*)(Xw + swz(cpS * 256 + tid * 16));
        *(uint4*)(Xw + swz(tid * 16)) = v;
    }
}

// ---------------------------------------------------------------------------
// Fused tree kernel v13: ONE ITEM PER BLOCK, 512 blocks, <=78KB LDS ->
// 2 blocks/CU co-resident (16 waves/CU): two independent level chains
// overlap each other's barrier/latency stalls. W1+W2 in regs (116 VGPR).
// ---------------------------------------------------------------------------
__global__ void __launch_bounds__(512)
__attribute__((amdgpu_waves_per_eu(4)))
tree_kernel(
    const float* __restrict__ args, const int2* __restrict__ itemTab,
    const ushort* __restrict__ W1p, const ushort* __restrict__ W2p,
    const float* __restrict__ b1, const float* __restrict__ b2,
    const float* __restrict__ lnw, const float* __restrict__ lnb,
    float* __restrict__ out)
{
    __shared__ __align__(16) char Xw[65536];        // 256 element rows x 256B
    __shared__ unsigned int schedAll[1024];         // 8 levels x 128 entries
    __shared__ float2 pbuf[1024];                   // LN partials [wave][pair]
    __shared__ int cpSAll[8];
    __shared__ int nPAll[8];

    const int tid = threadIdx.x, lane = tid & 63, w = tid >> 6;

    // ---- one-time: W1 slice -> regs (wave w owns H cols 32w..32w+31)
    uint4 w1r[8][2];
    #pragma unroll
    for (int kk = 0; kk < 8; ++kk)
        #pragma unroll
        for (int n = 0; n < 2; ++n)
            w1r[kk][n] = *(const uint4*)(W1p + (size_t)(((kk * 16 + (w * 2 + n)) * 64 + lane) << 3));

    // ---- one-time: W2 slice -> regs (wave w owns Y cols 16w..16w+15)
    uint4 w2r[8];
    #pragma unroll
    for (int kk = 0; kk < 8; ++kk)
        w2r[kk] = *(const uint4*)(W2p + (size_t)(((kk * 8 + w) * 64 + lane) << 3));

    float bb1[2][4];
    #pragma unroll
    for (int n = 0; n < 2; ++n)
        #pragma unroll
        for (int i = 0; i < 4; ++i)
            bb1[n][i] = b1[32 * w + 16 * n + 4 * (lane >> 4) + i];
    float bb2v[4], lwv[4], lbv[4];
    #pragma unroll
    for (int i = 0; i < 4; ++i) {
        int c = 16 * w + 4 * (lane >> 4) + i;
        bb2v[i] = b2[c]; lwv[i] = lnw[c]; lbv[i] = lnb[c];
    }

    const int2 it2 = itemTab[blockIdx.x];
    const int iOut = it2.x & 0xFFFF;
    const int L0   = it2.x >> 16;
    const int r0   = it2.y;
    const int nlev = (L0 > 1) ? (32 - __clz(L0 - 1)) : 0;

    // ---- phase A: wave0 builds all-level schedules (pure arithmetic);
    //      waves 1..7 stage leaves
    if (w == 0) {
        int l = L0;
        for (int k = 0; k < nlev; ++k) {
            int pA = l >> 1;
            if (lane == 0) {
                nPAll[k]  = pA;
                cpSAll[k] = (l > 1 && (l & 1)) ? (l - 1) : 0xFFFF;
            }
            #pragma unroll
            for (int rep = 0; rep < 2; ++rep) {
                int e = lane + rep * 64;
                unsigned entry = (e < pA)
                    ? ((unsigned)e | ((unsigned)((l & 1) + e) << 16))
                    : 0xFFFF0000u;
                schedAll[k * 128 + e] = entry;
            }
            l = pA + (l & 1);
        }
    } else {
        const int njob = L0 * 16;
        for (int job = tid - 64; job < njob; job += 448) {
            int r = job >> 4, ch = job & 15;
            int src = r0 + r;
            const float4 f0 = *(const float4*)(args + (size_t)src * D + ch * 8);
            const float4 f1 = *(const float4*)(args + (size_t)src * D + ch * 8 + 4);
            uint4 pk;
            pk.x = (uint)f2b(f0.x) | ((uint)f2b(f0.y) << 16);
            pk.y = (uint)f2b(f0.z) | ((uint)f2b(f0.w) << 16);
            pk.z = (uint)f2b(f1.x) | ((uint)f2b(f1.y) << 16);
            pk.w = (uint)f2b(f1.z) | ((uint)f2b(f1.w) << 16);
            *(uint4*)(Xw + swz(r * 256 + ch * 16)) = pk;
        }
    }
    __syncthreads();

    // ---- level loop (nP <= 128 always; no chunking)
    for (int k = 0; k < nlev; ++k) {
        const int nP = nPAll[k];
        if (nP == 0) break;
        const int nMf = (nP + 15) >> 4;
        const unsigned* sk = schedAll + k * 128;
        const int cpS = cpSAll[k];
        if (nMf > 4)
            level_body<8>(Xw, sk, w1r, w2r, bb1, bb2v, lwv, lbv, pbuf, cpS, tid, lane, w);
        else if (nMf > 2)
            level_body<4>(Xw, sk, w1r, w2r, bb1, bb2v, lwv, lbv, pbuf, cpS, tid, lane, w);
        else if (nMf == 2)
            level_body<2>(Xw, sk, w1r, w2r, bb1, bb2v, lwv, lbv, pbuf, cpS, tid, lane, w);
        else
            level_body<1>(Xw, sk, w1r, w2r, bb1, bb2v, lwv, lbv, pbuf, cpS, tid, lane, w);
        __syncthreads();
    }

    // ---- output: root = live row 0; L==1 exact f32 from args
    if (tid < 32) {
        int grp = tid;
        float4 o;
        if (L0 == 1) {
            o = *(const float4*)(args + (size_t)r0 * D + grp * 4);
        } else {
            uint2 v = *(const uint2*)(Xw + swz(grp * 8));
            o.x = b2f((ushort)(v.x & 0xFFFFu));
            o.y = b2f((ushort)(v.x >> 16));
            o.z = b2f((ushort)(v.y & 0xFFFFu));
            o.w = b2f((ushort)(v.y >> 16));
        }
        *(float4*)(out + (size_t)iOut * D + grp * 4) = o;
    }
}

// ---------------------------------------------------------------------------
extern "C" void kernel_launch(void* const* d_in, const int* in_sizes, int n_in,
                              void* d_out, int out_size, void* d_ws, size_t ws_size,
                              hipStream_t stream) {
    const float* args   = (const float*)d_in[0];
    const int*   limits = (const int*)d_in[1];     // harness: integer -> const int*
    const float* W1     = (const float*)d_in[2];
    const float* b1     = (const float*)d_in[3];
    const float* W2     = (const float*)d_in[4];
    const float* b2     = (const float*)d_in[5];
    const float* lnw    = (const float*)d_in[6];
    const float* lnb    = (const float*)d_in[7];

    char* ws = (char*)d_ws;
    ushort* W1p     = (ushort*)(ws);              // 131072 B
    ushort* W2p     = (ushort*)(ws + 131072);     //  65536 B
    int2*   itemTab = (int2*)  (ws + 196608);     //   4096 B

    prep_kernel<<<193, 512, 0, stream>>>(W1, W2, limits, W1p, W2p, itemTab);
    tree_kernel<<<512, 512, 0, stream>>>(args, itemTab, W1p, W2p, b1, b2, lnw, lnb,
                                         (float*)d_out);
}

// Round 15
// 82.557 us; speedup vs baseline: 2.1903x; 2.1903x over previous
//
#include <hip/hip_runtime.h>
#include <stdint.h>

#define D 128

typedef __bf16 bf16x8 __attribute__((ext_vector_type(8)));
typedef float f32x4  __attribute__((ext_vector_type(4)));

__device__ __forceinline__ float b2f(ushort u) {
    uint x = ((uint)u) << 16;
    return __builtin_bit_cast(float, x);
}
__device__ __forceinline__ ushort f2b(float f) {   // round-to-nearest-even
    uint u = __builtin_bit_cast(uint, f);
    u += 0x7FFFu + ((u >> 16) & 1u);
    return (ushort)(u >> 16);
}
// swizzle: XOR low-3 bits of the 16B slot with the 512B pair-row index
__device__ __forceinline__ int swz(int b) { return b ^ (((b >> 9) & 7) << 4); }

// ---------------------------------------------------------------------------
// prep: blocks 0..191 pack weights (fragment-major bf16); block 192 builds
// the rank-interleaved item table: tab[2c]=rank c, tab[2c+1]=rank 511-c,
// so any 2-block grouping a CU receives sums to ~T/256 rows.
// ---------------------------------------------------------------------------
__global__ void __launch_bounds__(512) prep_kernel(
    const float* __restrict__ W1, const float* __restrict__ W2,
    const int* __restrict__ limits,
    ushort* __restrict__ W1p, ushort* __restrict__ W2p,
    int2* __restrict__ itemTab)
{
    if (blockIdx.x < 192) {
        int g = blockIdx.x * 512 + threadIdx.x;
        if (g < 65536) {
            int t = g & 7, l = (g >> 3) & 63, nt = (g >> 9) & 15, kk = g >> 13;
            int krow = kk * 32 + (l >> 4) * 8 + t;
            int col  = nt * 16 + (l & 15);
            W1p[g] = f2b(W1[krow * 256 + col]);
        } else {
            int g2 = g - 65536;
            int t = g2 & 7, l = (g2 >> 3) & 63, nt = (g2 >> 9) & 7, kk = g2 >> 12;
            int krow = kk * 32 + (l >> 4) * 8 + t;
            int col  = nt * 16 + (l & 15);
            W2p[g2] = f2b(W2[krow * 128 + col]);
        }
        return;
    }
    // ---- rank items by descending L; interleave big/small
    __shared__ ushort Ls[512];
    __shared__ ushort rnkIdx[512];
    const int tid = threadIdx.x;
    int Lm = min(max(limits[tid + 1] - limits[tid], 1), 256);
    Ls[tid] = (ushort)Lm;
    __syncthreads();
    int rank = 0;
    for (int j = 0; j < 512; ++j) {
        int Lj = Ls[j];
        rank += (Lj > Lm) || (Lj == Lm && j < tid);
    }
    rnkIdx[rank] = (ushort)tid;
    __syncthreads();
    if (tid < 256) {
        int iA = rnkIdx[tid], iB = rnkIdx[511 - tid];
        itemTab[2 * tid]     = int2{ iA | (((int)Ls[iA]) << 16), limits[iA] };
        itemTab[2 * tid + 1] = int2{ iB | (((int)Ls[iB]) << 16), limits[iB] };
    }
}

// ---------------------------------------------------------------------------
// Level body, compile-time NMF (<=8 fragments = <=128 pairs; G==1).
// GEMM1: multipass FPP=2, W1 in regs. GEMM2: operand-swapped N-split-8,
// W2 in regs. LN: 2-shfl partials -> pbuf -> cross-wave combine.
// ---------------------------------------------------------------------------
template<int NMF>
__device__ __forceinline__ void level_body(
    char* __restrict__ Xw, const unsigned* __restrict__ sk,
    const uint4 (&w1r)[8][2], const uint4 (&w2r)[8],
    const float (&bb1)[2][4], const float (&bb2v)[4],
    const float (&lwv)[4], const float (&lbv)[4],
    float2* __restrict__ pbuf, int cpS,
    int tid, int lane, int w)
{
    constexpr int FPP   = (NMF >= 2) ? 2 : 1;
    constexpr int NPASS = NMF / FPP;

    // ---- GEMM1 (swapped, N-split-8), FPP fragments per pass ----
    #pragma unroll
    for (int p = 0; p < NPASS; ++p) {
        unsigned pa[FPP];
        #pragma unroll
        for (int mf = 0; mf < FPP; ++mf) pa[mf] = sk[(p * FPP + mf) * 16 + (lane & 15)];

        f32x4 acc1[2][FPP];
        #pragma unroll
        for (int n = 0; n < 2; ++n)
            #pragma unroll
            for (int mf = 0; mf < FPP; ++mf) acc1[n][mf] = f32x4{0.f, 0.f, 0.f, 0.f};

        #pragma unroll
        for (int kk = 0; kk < 8; ++kk) {
            uint4 xv[FPP];
            #pragma unroll
            for (int mf = 0; mf < FPP; ++mf) {
                int prow = (int)(pa[mf] & 0xFFFFu);
                xv[mf] = *(const uint4*)(Xw + (prow * 512 + ((kk * 64 + (lane >> 4) * 16) ^ ((prow & 7) << 4))));
            }
            #pragma unroll
            for (int n = 0; n < 2; ++n) {
                bf16x8 af = __builtin_bit_cast(bf16x8, w1r[kk][n]);
                #pragma unroll
                for (int mf = 0; mf < FPP; ++mf)
                    acc1[n][mf] = __builtin_amdgcn_mfma_f32_16x16x32_bf16(
                        af, __builtin_bit_cast(bf16x8, xv[mf]), acc1[n][mf], 0, 0, 0);
            }
        }
        __syncthreads();   // all waves' X reads for this pass done

        // H write-back for this pass (lane holds 4 consecutive H cols)
        #pragma unroll
        for (int mf = 0; mf < FPP; ++mf) {
            if ((pa[mf] >> 16) != 0xFFFFu) {
                int prow = (int)(pa[mf] & 0xFFFFu);
                int rbase = prow * 512, sm = (prow & 7) << 4;
                #pragma unroll
                for (int n = 0; n < 2; ++n) {
                    float h0 = fmaxf(acc1[n][mf][0] + bb1[n][0], 0.f);
                    float h1 = fmaxf(acc1[n][mf][1] + bb1[n][1], 0.f);
                    float h2 = fmaxf(acc1[n][mf][2] + bb1[n][2], 0.f);
                    float h3 = fmaxf(acc1[n][mf][3] + bb1[n][3], 0.f);
                    uint2 pk;
                    pk.x = (uint)f2b(h0) | ((uint)f2b(h1) << 16);
                    pk.y = (uint)f2b(h2) | ((uint)f2b(h3) << 16);
                    *(uint2*)(Xw + (rbase + ((64 * w + 32 * n + 8 * (lane >> 4)) ^ sm))) = pk;
                }
            }
        }
    }
    __syncthreads();   // final pass's H visible

    // ---- GEMM2 swapped: acc2[mf] = Y^T fragment for wave's 16 Y-cols ----
    unsigned pa2[NMF];
    #pragma unroll
    for (int mf = 0; mf < NMF; ++mf) pa2[mf] = sk[mf * 16 + (lane & 15)];

    f32x4 acc2[NMF];
    #pragma unroll
    for (int mf = 0; mf < NMF; ++mf) acc2[mf] = f32x4{0.f, 0.f, 0.f, 0.f};

    #pragma unroll
    for (int kk = 0; kk < 8; ++kk) {
        bf16x8 af = __builtin_bit_cast(bf16x8, w2r[kk]);
        #pragma unroll
        for (int mf = 0; mf < NMF; ++mf) {
            int prow = (int)(pa2[mf] & 0xFFFFu);
            uint4 hv = *(const uint4*)(Xw + (prow * 512 + ((kk * 64 + (lane >> 4) * 16) ^ ((prow & 7) << 4))));
            acc2[mf] = __builtin_amdgcn_mfma_f32_16x16x32_bf16(
                af, __builtin_bit_cast(bf16x8, hv), acc2[mf], 0, 0, 0);
        }
    }

    // bias + 16-col LN partials -> pbuf[w][pair]
    #pragma unroll
    for (int mf = 0; mf < NMF; ++mf) {
        float s1 = 0.f, s2 = 0.f;
        #pragma unroll
        for (int i = 0; i < 4; ++i) {
            float v = acc2[mf][i] + bb2v[i];
            acc2[mf][i] = v; s1 += v; s2 += v * v;
        }
        s1 += __shfl_xor(s1, 16, 64); s2 += __shfl_xor(s2, 16, 64);
        s1 += __shfl_xor(s1, 32, 64); s2 += __shfl_xor(s2, 32, 64);
        if ((lane >> 4) == 0)
            pbuf[w * 128 + mf * 16 + (lane & 15)] = float2{s1, s2};
    }
    __syncthreads();   // H reads done + partials visible

    // combine partials, normalize, write Y (4 consecutive cols per lane)
    #pragma unroll
    for (int mf = 0; mf < NMF; ++mf) {
        int yd = (int)(pa2[mf] >> 16);
        if (yd != 0xFFFF) {
            int p = mf * 16 + (lane & 15);
            float S1 = 0.f, S2 = 0.f;
            #pragma unroll
            for (int ww = 0; ww < 8; ++ww) {
                float2 o = pbuf[ww * 128 + p];
                S1 += o.x; S2 += o.y;
            }
            float mu = S1 * (1.f / 128.f);
            float var = S2 * (1.f / 128.f) - mu * mu;
            float rs = rsqrtf(var + 1e-5f);
            float v0 = (acc2[mf][0] - mu) * rs * lwv[0] + lbv[0];
            float v1 = (acc2[mf][1] - mu) * rs * lwv[1] + lbv[1];
            float v2 = (acc2[mf][2] - mu) * rs * lwv[2] + lbv[2];
            float v3 = (acc2[mf][3] - mu) * rs * lwv[3] + lbv[3];
            uint2 pk;
            pk.x = (uint)f2b(v0) | ((uint)f2b(v1) << 16);
            pk.y = (uint)f2b(v2) | ((uint)f2b(v3) << 16);
            *(uint2*)(Xw + swz(yd * 256 + (16 * w + 4 * (lane >> 4)) * 2)) = pk;
        }
    }
    // leftover row: copy row (l-1) -> row 0 (odd level); 16 chunks, tid<16
    if (cpS != 0xFFFF && tid < 16) {
        uint4 v = *(const uint4*)(Xw + swz(cpS * 256 + tid * 16));
        *(uint4*)(Xw + swz(tid * 16)) = v;
    }
}

// ---------------------------------------------------------------------------
// Fused tree kernel v14: ONE ITEM PER BLOCK, 512 blocks, 78KB LDS. Plain
// __launch_bounds__(512) (cap 256 VGPR): compiler allocates the natural
// ~116 regs (no spill, unlike r14's waves_per_eu(4) -> 64-reg split). With
// VGPR<=128 the HW grants 4 waves/EU -> 2 blocks/CU co-resident: two
// independent level chains overlap each other's barrier/latency stalls.
// ---------------------------------------------------------------------------
__global__ void __launch_bounds__(512)
tree_kernel(
    const float* __restrict__ args, const int2* __restrict__ itemTab,
    const ushort* __restrict__ W1p, const ushort* __restrict__ W2p,
    const float* __restrict__ b1, const float* __restrict__ b2,
    const float* __restrict__ lnw, const float* __restrict__ lnb,
    float* __restrict__ out)
{
    __shared__ __align__(16) char Xw[65536];        // 256 element rows x 256B
    __shared__ unsigned int schedAll[1024];         // 8 levels x 128 entries
    __shared__ float2 pbuf[1024];                   // LN partials [wave][pair]
    __shared__ int cpSAll[8];
    __shared__ int nPAll[8];

    const int tid = threadIdx.x, lane = tid & 63, w = tid >> 6;

    // ---- one-time: W1 slice -> regs (wave w owns H cols 32w..32w+31)
    uint4 w1r[8][2];
    #pragma unroll
    for (int kk = 0; kk < 8; ++kk)
        #pragma unroll
        for (int n = 0; n < 2; ++n)
            w1r[kk][n] = *(const uint4*)(W1p + (size_t)(((kk * 16 + (w * 2 + n)) * 64 + lane) << 3));

    // ---- one-time: W2 slice -> regs (wave w owns Y cols 16w..16w+15)
    uint4 w2r[8];
    #pragma unroll
    for (int kk = 0; kk < 8; ++kk)
        w2r[kk] = *(const uint4*)(W2p + (size_t)(((kk * 8 + w) * 64 + lane) << 3));

    float bb1[2][4];
    #pragma unroll
    for (int n = 0; n < 2; ++n)
        #pragma unroll
        for (int i = 0; i < 4; ++i)
            bb1[n][i] = b1[32 * w + 16 * n + 4 * (lane >> 4) + i];
    float bb2v[4], lwv[4], lbv[4];
    #pragma unroll
    for (int i = 0; i < 4; ++i) {
        int c = 16 * w + 4 * (lane >> 4) + i;
        bb2v[i] = b2[c]; lwv[i] = lnw[c]; lbv[i] = lnb[c];
    }

    const int2 it2 = itemTab[blockIdx.x];
    const int iOut = it2.x & 0xFFFF;
    const int L0   = it2.x >> 16;
    const int r0   = it2.y;
    const int nlev = (L0 > 1) ? (32 - __clz(L0 - 1)) : 0;

    // ---- phase A: wave0 builds all-level schedules (pure arithmetic);
    //      waves 1..7 stage leaves
    if (w == 0) {
        int l = L0;
        for (int k = 0; k < nlev; ++k) {
            int pA = l >> 1;
            if (lane == 0) {
                nPAll[k]  = pA;
                cpSAll[k] = (l > 1 && (l & 1)) ? (l - 1) : 0xFFFF;
            }
            #pragma unroll
            for (int rep = 0; rep < 2; ++rep) {
                int e = lane + rep * 64;
                unsigned entry = (e < pA)
                    ? ((unsigned)e | ((unsigned)((l & 1) + e) << 16))
                    : 0xFFFF0000u;
                schedAll[k * 128 + e] = entry;
            }
            l = pA + (l & 1);
        }
    } else {
        const int njob = L0 * 16;
        for (int job = tid - 64; job < njob; job += 448) {
            int r = job >> 4, ch = job & 15;
            int src = r0 + r;
            const float4 f0 = *(const float4*)(args + (size_t)src * D + ch * 8);
            const float4 f1 = *(const float4*)(args + (size_t)src * D + ch * 8 + 4);
            uint4 pk;
            pk.x = (uint)f2b(f0.x) | ((uint)f2b(f0.y) << 16);
            pk.y = (uint)f2b(f0.z) | ((uint)f2b(f0.w) << 16);
            pk.z = (uint)f2b(f1.x) | ((uint)f2b(f1.y) << 16);
            pk.w = (uint)f2b(f1.z) | ((uint)f2b(f1.w) << 16);
            *(uint4*)(Xw + swz(r * 256 + ch * 16)) = pk;
        }
    }
    __syncthreads();

    // ---- level loop (nP <= 128 always; no chunking)
    for (int k = 0; k < nlev; ++k) {
        const int nP = nPAll[k];
        if (nP == 0) break;
        const int nMf = (nP + 15) >> 4;
        const unsigned* sk = schedAll + k * 128;
        const int cpS = cpSAll[k];
        if (nMf > 4)
            level_body<8>(Xw, sk, w1r, w2r, bb1, bb2v, lwv, lbv, pbuf, cpS, tid, lane, w);
        else if (nMf > 2)
            level_body<4>(Xw, sk, w1r, w2r, bb1, bb2v, lwv, lbv, pbuf, cpS, tid, lane, w);
        else if (nMf == 2)
            level_body<2>(Xw, sk, w1r, w2r, bb1, bb2v, lwv, lbv, pbuf, cpS, tid, lane, w);
        else
            level_body<1>(Xw, sk, w1r, w2r, bb1, bb2v, lwv, lbv, pbuf, cpS, tid, lane, w);
        __syncthreads();
    }

    // ---- output: root = live row 0; L==1 exact f32 from args
    if (tid < 32) {
        int grp = tid;
        float4 o;
        if (L0 == 1) {
            o = *(const float4*)(args + (size_t)r0 * D + grp * 4);
        } else {
            uint2 v = *(const uint2*)(Xw + swz(grp * 8));
            o.x = b2f((ushort)(v.x & 0xFFFFu));
            o.y = b2f((ushort)(v.x >> 16));
            o.z = b2f((ushort)(v.y & 0xFFFFu));
            o.w = b2f((ushort)(v.y >> 16));
        }
        *(float4*)(out + (size_t)iOut * D + grp * 4) = o;
    }
}

// ---------------------------------------------------------------------------
extern "C" void kernel_launch(void* const* d_in, const int* in_sizes, int n_in,
                              void* d_out, int out_size, void* d_ws, size_t ws_size,
                              hipStream_t stream) {
    const float* args   = (const float*)d_in[0];
    const int*   limits = (const int*)d_in[1];     // harness: integer -> const int*
    const float* W1     = (const float*)d_in[2];
    const float* b1     = (const float*)d_in[3];
    const float* W2     = (const float*)d_in[4];
    const float* b2     = (const float*)d_in[5];
    const float* lnw    = (const float*)d_in[6];
    const float* lnb    = (const float*)d_in[7];

    char* ws = (char*)d_ws;
    ushort* W1p     = (ushort*)(ws);              // 131072 B
    ushort* W2p     = (ushort*)(ws + 131072);     //  65536 B
    int2*   itemTab = (int2*)  (ws + 196608);     //   4096 B

    prep_kernel<<<193, 512, 0, stream>>>(W1, W2, limits, W1p, W2p, itemTab);
    tree_kernel<<<512, 512, 0, stream>>>(args, itemTab, W1p, W2p, b1, b2, lnw, lnb,
                                         (float*)d_out);
}

// Round 16
// 66.704 us; speedup vs baseline: 2.7109x; 1.2377x over previous
//
#include <hip/hip_runtime.h>
#include <stdint.h>

#define D 128

typedef __bf16 bf16x8 __attribute__((ext_vector_type(8)));
typedef float f32x4  __attribute__((ext_vector_type(4)));

__device__ __forceinline__ float b2f(ushort u) {
    uint x = ((uint)u) << 16;
    return __builtin_bit_cast(float, x);
}
__device__ __forceinline__ ushort f2b(float f) {   // round-to-nearest-even
    uint u = __builtin_bit_cast(uint, f);
    u += 0x7FFFu + ((u >> 16) & 1u);
    return (ushort)(u >> 16);
}
// swizzle: XOR low-3 bits of the 16B slot with the 512B pair-row index
__device__ __forceinline__ int swz(int b) { return b ^ (((b >> 9) & 7) << 4); }

// ---------------------------------------------------------------------------
// Level body, compile-time NMF (<=8 fragments = <=128 pairs per call).
// GEMM1: multipass FPP=4 (acc1[2][4]=32 regs), W1 in regs.
// GEMM2: operand-swapped N-split-8, W2 in regs.
// LN: 2-shfl partials -> pbuf -> cross-wave combine. doLeft gates leftover.
// ---------------------------------------------------------------------------
template<int NMF>
__device__ __forceinline__ void level_body(
    char* __restrict__ Xw, const unsigned* __restrict__ sk,
    const uint4 (&w1r)[8][2], const uint4 (&w2r)[8],
    const float (&bb1)[2][4], const float (&bb2v)[4],
    const float (&lwv)[4], const float (&lbv)[4],
    float2* __restrict__ pbuf,
    const ushort* __restrict__ cpSk, const ushort* __restrict__ itOff,
    int G, bool doLeft, int tid, int lane, int w)
{
    constexpr int FPP   = (NMF >= 4) ? 4 : NMF;
    constexpr int NPASS = NMF / FPP;

    // ---- GEMM1 (swapped, N-split-8), FPP fragments per pass ----
    #pragma unroll
    for (int p = 0; p < NPASS; ++p) {
        unsigned pa[FPP];
        #pragma unroll
        for (int mf = 0; mf < FPP; ++mf) pa[mf] = sk[(p * FPP + mf) * 16 + (lane & 15)];

        f32x4 acc1[2][FPP];
        #pragma unroll
        for (int n = 0; n < 2; ++n)
            #pragma unroll
            for (int mf = 0; mf < FPP; ++mf) acc1[n][mf] = f32x4{0.f, 0.f, 0.f, 0.f};

        #pragma unroll
        for (int kk = 0; kk < 8; ++kk) {
            uint4 xv[FPP];
            #pragma unroll
            for (int mf = 0; mf < FPP; ++mf) {
                int prow = (int)(pa[mf] & 0xFFFFu);
                xv[mf] = *(const uint4*)(Xw + (prow * 512 + ((kk * 64 + (lane >> 4) * 16) ^ ((prow & 7) << 4))));
            }
            #pragma unroll
            for (int n = 0; n < 2; ++n) {
                bf16x8 af = __builtin_bit_cast(bf16x8, w1r[kk][n]);
                #pragma unroll
                for (int mf = 0; mf < FPP; ++mf)
                    acc1[n][mf] = __builtin_amdgcn_mfma_f32_16x16x32_bf16(
                        af, __builtin_bit_cast(bf16x8, xv[mf]), acc1[n][mf], 0, 0, 0);
            }
        }
        __syncthreads();   // all waves' X reads for this pass done

        // H write-back for this pass (lane holds 4 consecutive H cols)
        #pragma unroll
        for (int mf = 0; mf < FPP; ++mf) {
            if ((pa[mf] >> 16) != 0xFFFFu) {
                int prow = (int)(pa[mf] & 0xFFFFu);
                int rbase = prow * 512, sm = (prow & 7) << 4;
                #pragma unroll
                for (int n = 0; n < 2; ++n) {
                    float h0 = fmaxf(acc1[n][mf][0] + bb1[n][0], 0.f);
                    float h1 = fmaxf(acc1[n][mf][1] + bb1[n][1], 0.f);
                    float h2 = fmaxf(acc1[n][mf][2] + bb1[n][2], 0.f);
                    float h3 = fmaxf(acc1[n][mf][3] + bb1[n][3], 0.f);
                    uint2 pk;
                    pk.x = (uint)f2b(h0) | ((uint)f2b(h1) << 16);
                    pk.y = (uint)f2b(h2) | ((uint)f2b(h3) << 16);
                    *(uint2*)(Xw + (rbase + ((64 * w + 32 * n + 8 * (lane >> 4)) ^ sm))) = pk;
                }
            }
        }
    }
    __syncthreads();   // final pass's H visible

    // ---- GEMM2 swapped: acc2[mf] = Y^T fragment for wave's 16 Y-cols ----
    unsigned pa2[NMF];
    #pragma unroll
    for (int mf = 0; mf < NMF; ++mf) pa2[mf] = sk[mf * 16 + (lane & 15)];

    f32x4 acc2[NMF];
    #pragma unroll
    for (int mf = 0; mf < NMF; ++mf) acc2[mf] = f32x4{0.f, 0.f, 0.f, 0.f};

    #pragma unroll
    for (int kk = 0; kk < 8; ++kk) {
        bf16x8 af = __builtin_bit_cast(bf16x8, w2r[kk]);
        #pragma unroll
        for (int mf = 0; mf < NMF; ++mf) {
            int prow = (int)(pa2[mf] & 0xFFFFu);
            uint4 hv = *(const uint4*)(Xw + (prow * 512 + ((kk * 64 + (lane >> 4) * 16) ^ ((prow & 7) << 4))));
            acc2[mf] = __builtin_amdgcn_mfma_f32_16x16x32_bf16(
                af, __builtin_bit_cast(bf16x8, hv), acc2[mf], 0, 0, 0);
        }
    }

    // bias + 16-col LN partials -> pbuf[w][pair]
    #pragma unroll
    for (int mf = 0; mf < NMF; ++mf) {
        float s1 = 0.f, s2 = 0.f;
        #pragma unroll
        for (int i = 0; i < 4; ++i) {
            float v = acc2[mf][i] + bb2v[i];
            acc2[mf][i] = v; s1 += v; s2 += v * v;
        }
        s1 += __shfl_xor(s1, 16, 64); s2 += __shfl_xor(s2, 16, 64);
        s1 += __shfl_xor(s1, 32, 64); s2 += __shfl_xor(s2, 32, 64);
        if ((lane >> 4) == 0)
            pbuf[w * 128 + mf * 16 + (lane & 15)] = float2{s1, s2};
    }
    __syncthreads();   // H reads done + partials visible

    // combine partials, normalize, write Y (4 consecutive cols per lane)
    #pragma unroll
    for (int mf = 0; mf < NMF; ++mf) {
        int yd = (int)(pa2[mf] >> 16);
        if (yd != 0xFFFF) {
            int p = mf * 16 + (lane & 15);
            float S1 = 0.f, S2 = 0.f;
            #pragma unroll
            for (int ww = 0; ww < 8; ++ww) {
                float2 o = pbuf[ww * 128 + p];
                S1 += o.x; S2 += o.y;
            }
            float mu = S1 * (1.f / 128.f);
            float var = S2 * (1.f / 128.f) - mu * mu;
            float rs = rsqrtf(var + 1e-5f);
            float v0 = (acc2[mf][0] - mu) * rs * lwv[0] + lbv[0];
            float v1 = (acc2[mf][1] - mu) * rs * lwv[1] + lbv[1];
            float v2 = (acc2[mf][2] - mu) * rs * lwv[2] + lbv[2];
            float v3 = (acc2[mf][3] - mu) * rs * lwv[3] + lbv[3];
            uint2 pk;
            pk.x = (uint)f2b(v0) | ((uint)f2b(v1) << 16);
            pk.y = (uint)f2b(v2) | ((uint)f2b(v3) << 16);
            *(uint2*)(Xw + swz(yd * 256 + (16 * w + 4 * (lane >> 4)) * 2)) = pk;
        }
    }
    // leftover rows: copy row (l-1) -> row itOff per odd item (last chunk only)
    if (doLeft) {
        #pragma unroll
        for (int q = 0; q < 2; ++q) {
            int it = q * 32 + (tid >> 4);
            if (it < G) {
                int srow = (int)cpSk[it];
                if (srow != 0xFFFF) {
                    int ch = tid & 15;
                    uint4 v = *(const uint4*)(Xw + swz(srow * 256 + ch * 16));
                    *(uint4*)(Xw + swz((int)itOff[it] * 256 + ch * 16)) = v;
                }
            }
        }
    }
}

// ---------------------------------------------------------------------------
// Fused tree kernel v15 = round-13 v12 structure made SINGLE-KERNEL:
// each block computes its own chain (in-kernel 512-thread ranking) and packs
// its own W1/W2 register slices directly from f32 (L3-hot). Chain-per-block,
// Xw=352 rows, W1+W2 in regs, swapped GEMMs, FPP=4 multipass.
// ---------------------------------------------------------------------------
__global__ void __launch_bounds__(512)
__attribute__((amdgpu_waves_per_eu(2, 2)))
tree_kernel(
    const float* __restrict__ args, const int* __restrict__ limits,
    const float* __restrict__ W1, const float* __restrict__ W2,
    const float* __restrict__ b1, const float* __restrict__ b2,
    const float* __restrict__ lnw, const float* __restrict__ lnb,
    float* __restrict__ out)
{
    __shared__ __align__(16) char Xw[90112];        // 352 element rows x 256B
    __shared__ unsigned int schedAll[1536];         // 8 levels x 192 entries
    __shared__ float2 pbuf[1024];                   // LN partials [wave][pair]
    __shared__ ushort Ls[512];
    __shared__ int plan[4];                         // iA|La<<16, iB|Lb<<16, a0A, a0B
    __shared__ ushort cpSAll[8][2];
    __shared__ ushort itOff[2], itL[2], itOut[2];
    __shared__ int itRow[2];
    __shared__ int nPAll[8];

    const int tid = threadIdx.x, lane = tid & 63, w = tid >> 6;

    // ---- one-time: W1 slice -> regs directly from f32 (wave w: H cols 32w..32w+31)
    uint4 w1r[8][2];
    #pragma unroll
    for (int kk = 0; kk < 8; ++kk)
        #pragma unroll
        for (int n = 0; n < 2; ++n) {
            const float* src = W1 + (size_t)(kk * 32 + (lane >> 4) * 8) * 256 + (w * 2 + n) * 16 + (lane & 15);
            uint r[4];
            #pragma unroll
            for (int h = 0; h < 4; ++h) {
                float a = src[(2 * h) * 256], bb = src[(2 * h + 1) * 256];
                r[h] = (uint)f2b(a) | ((uint)f2b(bb) << 16);
            }
            w1r[kk][n] = uint4{r[0], r[1], r[2], r[3]};
        }

    // ---- one-time: W2 slice -> regs directly from f32 (wave w: Y cols 16w..16w+15)
    uint4 w2r[8];
    #pragma unroll
    for (int kk = 0; kk < 8; ++kk) {
        const float* src = W2 + (size_t)(kk * 32 + (lane >> 4) * 8) * 128 + w * 16 + (lane & 15);
        uint r[4];
        #pragma unroll
        for (int h = 0; h < 4; ++h) {
            float a = src[(2 * h) * 128], bb = src[(2 * h + 1) * 128];
            r[h] = (uint)f2b(a) | ((uint)f2b(bb) << 16);
        }
        w2r[kk] = uint4{r[0], r[1], r[2], r[3]};
    }

    float bb1[2][4];
    #pragma unroll
    for (int n = 0; n < 2; ++n)
        #pragma unroll
        for (int i = 0; i < 4; ++i)
            bb1[n][i] = b1[32 * w + 16 * n + 4 * (lane >> 4) + i];
    float bb2v[4], lwv[4], lbv[4];
    #pragma unroll
    for (int i = 0; i < 4; ++i) {
        int c = 16 * w + 4 * (lane >> 4) + i;
        bb2v[i] = b2[c]; lwv[i] = lnw[c]; lbv[i] = lnb[c];
    }

    // ---- in-kernel planner: rank items by descending L (tie: lower idx first);
    //      this block's chain = {rank bid, rank 511-bid}
    {
        int lim0 = limits[tid], lim1 = limits[tid + 1];
        int Lm = min(max(lim1 - lim0, 1), 256);
        Ls[tid] = (ushort)Lm;
        __syncthreads();
        int rank = 0;
        for (int j = 0; j < 512; ++j) {
            int Lj = Ls[j];
            rank += (Lj > Lm) || (Lj == Lm && j < tid);
        }
        if (rank == (int)blockIdx.x)       { plan[0] = tid | (Lm << 16); plan[2] = lim0; }
        if (rank == 511 - (int)blockIdx.x) { plan[1] = tid | (Lm << 16); plan[3] = lim0; }
        __syncthreads();
    }
    const int iA = plan[0] & 0xFFFF, La = plan[0] >> 16;
    const int iB = plan[1] & 0xFFFF, Lb = plan[1] >> 16;
    const int a0A = plan[2], a0B = plan[3];
    const int offBfull = (La + 1) & ~1;            // even-aligned B origin
    const bool split = (offBfull + Lb > 352);      // Xw capacity (rarely hit)
    const int npass = split ? 2 : 1;

    for (int pass = 0; pass < npass; ++pass) {
        int G, L0, r0, o0, off1 = 0, L1 = 0, r1 = 0, o1 = 0;
        if (!split)          { G = 2; L0 = La; r0 = a0A; o0 = iA; off1 = offBfull; L1 = Lb; r1 = a0B; o1 = iB; }
        else if (pass == 0)  { G = 1; L0 = La; r0 = a0A; o0 = iA; }
        else                 { G = 1; L0 = Lb; r0 = a0B; o0 = iB; }

        __syncthreads();   // previous pass's LDS readers done
        if (tid == 0) {
            itOff[0] = 0;            itL[0] = (ushort)L0; itRow[0] = r0; itOut[0] = (ushort)o0;
            itOff[1] = (ushort)off1; itL[1] = (ushort)L1; itRow[1] = r1; itOut[1] = (ushort)o1;
        }
        int nlev = (L0 > 1) ? (32 - __clz(L0 - 1)) : 0;
        if (G > 1 && L1 > 1) nlev = max(nlev, 32 - __clz(L1 - 1));

        // ---- phase A: wave0 builds all-level schedules (pure arithmetic);
        //      waves 1..7 stage leaves (pure arithmetic item test)
        if (w == 0) {
            int lA_ = L0, lB_ = (G > 1) ? L1 : 0;
            for (int k = 0; k < nlev; ++k) {
                int pA = lA_ >> 1, pB = lB_ >> 1, nPk = pA + pB;
                if (lane == 0) {
                    nPAll[k] = nPk;
                    cpSAll[k][0] = (lA_ > 1 && (lA_ & 1)) ? (ushort)(lA_ - 1) : (ushort)0xFFFF;
                    cpSAll[k][1] = (lB_ > 1 && (lB_ & 1)) ? (ushort)(off1 + lB_ - 1) : (ushort)0xFFFF;
                }
                #pragma unroll
                for (int rep = 0; rep < 3; ++rep) {
                    int e = lane + rep * 64;
                    unsigned entry = 0xFFFF0000u;
                    if (e < pA)
                        entry = (unsigned)e | ((unsigned)((lA_ & 1) + e) << 16);
                    else if (e < nPk) {
                        int j = e - pA;
                        entry = (unsigned)((off1 >> 1) + j) | ((unsigned)(off1 + (lB_ & 1) + j) << 16);
                    }
                    schedAll[k * 192 + e] = entry;
                }
                lA_ = pA + (lA_ & 1);
                lB_ = pB + (lB_ & 1);
            }
        } else {
            for (int job = tid - 64; job < 5632; job += 448) {
                int r = job >> 4, ch = job & 15;
                int src = -1;
                if (r < L0) src = r0 + r;
                else if (G > 1 && r >= off1 && r < off1 + L1) src = r1 + (r - off1);
                if (src >= 0) {
                    const float4 f0 = *(const float4*)(args + (size_t)src * D + ch * 8);
                    const float4 f1 = *(const float4*)(args + (size_t)src * D + ch * 8 + 4);
                    uint4 pk;
                    pk.x = (uint)f2b(f0.x) | ((uint)f2b(f0.y) << 16);
                    pk.y = (uint)f2b(f0.z) | ((uint)f2b(f0.w) << 16);
                    pk.z = (uint)f2b(f1.x) | ((uint)f2b(f1.y) << 16);
                    pk.w = (uint)f2b(f1.z) | ((uint)f2b(f1.w) << 16);
                    *(uint4*)(Xw + swz(r * 256 + ch * 16)) = pk;
                }
            }
        }
        __syncthreads();

        // ---- level loop; levels >128 pairs run in 128-pair chunks
        for (int k = 0; k < nlev; ++k) {
            const int nP = nPAll[k];
            if (nP == 0) break;
            int done = 0;
            while (done < nP) {
                const int chunk = min(nP - done, 128);
                const int nMf = (chunk + 15) >> 4;
                const bool last = (done + chunk >= nP);
                const unsigned* sk = schedAll + k * 192 + done;
                if (nMf > 4)
                    level_body<8>(Xw, sk, w1r, w2r, bb1, bb2v, lwv, lbv, pbuf, cpSAll[k], itOff, G, last, tid, lane, w);
                else if (nMf > 2)
                    level_body<4>(Xw, sk, w1r, w2r, bb1, bb2v, lwv, lbv, pbuf, cpSAll[k], itOff, G, last, tid, lane, w);
                else if (nMf == 2)
                    level_body<2>(Xw, sk, w1r, w2r, bb1, bb2v, lwv, lbv, pbuf, cpSAll[k], itOff, G, last, tid, lane, w);
                else
                    level_body<1>(Xw, sk, w1r, w2r, bb1, bb2v, lwv, lbv, pbuf, cpSAll[k], itOff, G, last, tid, lane, w);
                __syncthreads();
                done += chunk;
            }
        }

        // ---- output: root = live row itOff of each item; L==1 exact f32
        for (int j = tid; j < G * 32; j += 512) {
            int it = j >> 5, grp = j & 31;
            float4 o;
            if ((int)itL[it] == 1) {
                o = *(const float4*)(args + (size_t)itRow[it] * D + grp * 4);
            } else {
                uint2 v = *(const uint2*)(Xw + swz((int)itOff[it] * 256 + grp * 8));
                o.x = b2f((ushort)(v.x & 0xFFFFu));
                o.y = b2f((ushort)(v.x >> 16));
                o.z = b2f((ushort)(v.y & 0xFFFFu));
                o.w = b2f((ushort)(v.y >> 16));
            }
            *(float4*)(out + (size_t)itOut[it] * D + grp * 4) = o;
        }
    }
}

// ---------------------------------------------------------------------------
extern "C" void kernel_launch(void* const* d_in, const int* in_sizes, int n_in,
                              void* d_out, int out_size, void* d_ws, size_t ws_size,
                              hipStream_t stream) {
    const float* args   = (const float*)d_in[0];
    const int*   limits = (const int*)d_in[1];     // harness: integer -> const int*
    const float* W1     = (const float*)d_in[2];
    const float* b1     = (const float*)d_in[3];
    const float* W2     = (const float*)d_in[4];
    const float* b2     = (const float*)d_in[5];
    const float* lnw    = (const float*)d_in[6];
    const float* lnb    = (const float*)d_in[7];

    tree_kernel<<<256, 512, 0, stream>>>(args, limits, W1, W2, b1, b2, lnw, lnb,
                                         (float*)d_out);
}

// Round 17
// 64.582 us; speedup vs baseline: 2.8000x; 1.0329x over previous
//
#include <hip/hip_runtime.h>
#include <stdint.h>

#define D 128

typedef __bf16 bf16x8 __attribute__((ext_vector_type(8)));
typedef float f32x4  __attribute__((ext_vector_type(4)));

__device__ __forceinline__ float b2f(ushort u) {
    uint x = ((uint)u) << 16;
    return __builtin_bit_cast(float, x);
}
__device__ __forceinline__ ushort f2b(float f) {   // round-to-nearest-even
    uint u = __builtin_bit_cast(uint, f);
    u += 0x7FFFu + ((u >> 16) & 1u);
    return (ushort)(u >> 16);
}
// swizzle: XOR low-3 bits of the 16B slot with the 512B pair-row index
__device__ __forceinline__ int swz(int b) { return b ^ (((b >> 9) & 7) << 4); }

// ---------------------------------------------------------------------------
// prep: blocks 0..191 pack weights (fragment-major bf16); block 192 builds
// the rank-paired chain table.
// ---------------------------------------------------------------------------
__global__ void __launch_bounds__(512) prep_kernel(
    const float* __restrict__ W1, const float* __restrict__ W2,
    const int* __restrict__ limits,
    ushort* __restrict__ W1p, ushort* __restrict__ W2p,
    int4* __restrict__ chainTab)
{
    if (blockIdx.x < 192) {
        int g = blockIdx.x * 512 + threadIdx.x;
        if (g < 65536) {
            int t = g & 7, l = (g >> 3) & 63, nt = (g >> 9) & 15, kk = g >> 13;
            int krow = kk * 32 + (l >> 4) * 8 + t;
            int col  = nt * 16 + (l & 15);
            W1p[g] = f2b(W1[krow * 256 + col]);
        } else {
            int g2 = g - 65536;
            int t = g2 & 7, l = (g2 >> 3) & 63, nt = (g2 >> 9) & 7, kk = g2 >> 12;
            int krow = kk * 32 + (l >> 4) * 8 + t;
            int col  = nt * 16 + (l & 15);
            W2p[g2] = f2b(W2[krow * 128 + col]);
        }
        return;
    }
    // ---- chain planner: rank by descending L, pair rank c with rank 511-c
    __shared__ ushort Ls[512];
    __shared__ ushort rnkIdx[512];
    const int tid = threadIdx.x;
    int Lm = min(max(limits[tid + 1] - limits[tid], 1), 256);
    Ls[tid] = (ushort)Lm;
    __syncthreads();
    int rank = 0;
    for (int j = 0; j < 512; ++j) {
        int Lj = Ls[j];
        rank += (Lj > Lm) || (Lj == Lm && j < tid);
    }
    rnkIdx[rank] = (ushort)tid;
    __syncthreads();
    if (tid < 256) {
        int iA = rnkIdx[tid], iB = rnkIdx[511 - tid];
        int4 t;
        t.x = iA | (((int)Ls[iA]) << 16);
        t.y = iB | (((int)Ls[iB]) << 16);
        t.z = limits[iA];
        t.w = limits[iB];
        chainTab[tid] = t;
    }
}

// ---------------------------------------------------------------------------
// Level body, compile-time NMF (<=8 fragments = <=128 pairs per call).
// GEMM1: multipass FPP=4 (acc1[2][4]=32 regs; NMF=8 -> 2 passes), W1 in regs.
// GEMM2: operand-swapped N-split-8, W2 in regs.
// LN: 2-shfl partials -> pbuf -> cross-wave combine. doLeft gates leftover.
// ---------------------------------------------------------------------------
template<int NMF>
__device__ __forceinline__ void level_body(
    char* __restrict__ Xw, const unsigned* __restrict__ sk,
    const uint4 (&w1r)[8][2], const uint4 (&w2r)[8],
    const float (&bb1)[2][4], const float (&bb2v)[4],
    const float (&lwv)[4], const float (&lbv)[4],
    float2* __restrict__ pbuf,
    const ushort* __restrict__ cpSk, const ushort* __restrict__ itOff,
    int G, bool doLeft, int tid, int lane, int w)
{
    constexpr int FPP   = (NMF >= 4) ? 4 : NMF;
    constexpr int NPASS = NMF / FPP;

    // ---- GEMM1 (swapped, N-split-8), FPP fragments per pass ----
    #pragma unroll
    for (int p = 0; p < NPASS; ++p) {
        unsigned pa[FPP];
        #pragma unroll
        for (int mf = 0; mf < FPP; ++mf) pa[mf] = sk[(p * FPP + mf) * 16 + (lane & 15)];

        f32x4 acc1[2][FPP];
        #pragma unroll
        for (int n = 0; n < 2; ++n)
            #pragma unroll
            for (int mf = 0; mf < FPP; ++mf) acc1[n][mf] = f32x4{0.f, 0.f, 0.f, 0.f};

        #pragma unroll
        for (int kk = 0; kk < 8; ++kk) {
            uint4 xv[FPP];
            #pragma unroll
            for (int mf = 0; mf < FPP; ++mf) {
                int prow = (int)(pa[mf] & 0xFFFFu);
                xv[mf] = *(const uint4*)(Xw + (prow * 512 + ((kk * 64 + (lane >> 4) * 16) ^ ((prow & 7) << 4))));
            }
            #pragma unroll
            for (int n = 0; n < 2; ++n) {
                bf16x8 af = __builtin_bit_cast(bf16x8, w1r[kk][n]);
                #pragma unroll
                for (int mf = 0; mf < FPP; ++mf)
                    acc1[n][mf] = __builtin_amdgcn_mfma_f32_16x16x32_bf16(
                        af, __builtin_bit_cast(bf16x8, xv[mf]), acc1[n][mf], 0, 0, 0);
            }
        }
        __syncthreads();   // all waves' X reads for this pass done

        // H write-back for this pass (lane holds 4 consecutive H cols)
        #pragma unroll
        for (int mf = 0; mf < FPP; ++mf) {
            if ((pa[mf] >> 16) != 0xFFFFu) {
                int prow = (int)(pa[mf] & 0xFFFFu);
                int rbase = prow * 512, sm = (prow & 7) << 4;
                #pragma unroll
                for (int n = 0; n < 2; ++n) {
                    float h0 = fmaxf(acc1[n][mf][0] + bb1[n][0], 0.f);
                    float h1 = fmaxf(acc1[n][mf][1] + bb1[n][1], 0.f);
                    float h2 = fmaxf(acc1[n][mf][2] + bb1[n][2], 0.f);
                    float h3 = fmaxf(acc1[n][mf][3] + bb1[n][3], 0.f);
                    uint2 pk;
                    pk.x = (uint)f2b(h0) | ((uint)f2b(h1) << 16);
                    pk.y = (uint)f2b(h2) | ((uint)f2b(h3) << 16);
                    *(uint2*)(Xw + (rbase + ((64 * w + 32 * n + 8 * (lane >> 4)) ^ sm))) = pk;
                }
            }
        }
    }
    __syncthreads();   // final pass's H visible

    // ---- GEMM2 swapped: acc2[mf] = Y^T fragment for wave's 16 Y-cols ----
    unsigned pa2[NMF];
    #pragma unroll
    for (int mf = 0; mf < NMF; ++mf) pa2[mf] = sk[mf * 16 + (lane & 15)];

    f32x4 acc2[NMF];
    #pragma unroll
    for (int mf = 0; mf < NMF; ++mf) acc2[mf] = f32x4{0.f, 0.f, 0.f, 0.f};

    #pragma unroll
    for (int kk = 0; kk < 8; ++kk) {
        bf16x8 af = __builtin_bit_cast(bf16x8, w2r[kk]);
        #pragma unroll
        for (int mf = 0; mf < NMF; ++mf) {
            int prow = (int)(pa2[mf] & 0xFFFFu);
            uint4 hv = *(const uint4*)(Xw + (prow * 512 + ((kk * 64 + (lane >> 4) * 16) ^ ((prow & 7) << 4))));
            acc2[mf] = __builtin_amdgcn_mfma_f32_16x16x32_bf16(
                af, __builtin_bit_cast(bf16x8, hv), acc2[mf], 0, 0, 0);
        }
    }

    // bias + 16-col LN partials -> pbuf[w][pair]
    #pragma unroll
    for (int mf = 0; mf < NMF; ++mf) {
        float s1 = 0.f, s2 = 0.f;
        #pragma unroll
        for (int i = 0; i < 4; ++i) {
            float v = acc2[mf][i] + bb2v[i];
            acc2[mf][i] = v; s1 += v; s2 += v * v;
        }
        s1 += __shfl_xor(s1, 16, 64); s2 += __shfl_xor(s2, 16, 64);
        s1 += __shfl_xor(s1, 32, 64); s2 += __shfl_xor(s2, 32, 64);
        if ((lane >> 4) == 0)
            pbuf[w * 128 + mf * 16 + (lane & 15)] = float2{s1, s2};
    }
    __syncthreads();   // H reads done + partials visible

    // combine partials, normalize, write Y (4 consecutive cols per lane)
    #pragma unroll
    for (int mf = 0; mf < NMF; ++mf) {
        int yd = (int)(pa2[mf] >> 16);
        if (yd != 0xFFFF) {
            int p = mf * 16 + (lane & 15);
            float S1 = 0.f, S2 = 0.f;
            #pragma unroll
            for (int ww = 0; ww < 8; ++ww) {
                float2 o = pbuf[ww * 128 + p];
                S1 += o.x; S2 += o.y;
            }
            float mu = S1 * (1.f / 128.f);
            float var = S2 * (1.f / 128.f) - mu * mu;
            float rs = rsqrtf(var + 1e-5f);
            float v0 = (acc2[mf][0] - mu) * rs * lwv[0] + lbv[0];
            float v1 = (acc2[mf][1] - mu) * rs * lwv[1] + lbv[1];
            float v2 = (acc2[mf][2] - mu) * rs * lwv[2] + lbv[2];
            float v3 = (acc2[mf][3] - mu) * rs * lwv[3] + lbv[3];
            uint2 pk;
            pk.x = (uint)f2b(v0) | ((uint)f2b(v1) << 16);
            pk.y = (uint)f2b(v2) | ((uint)f2b(v3) << 16);
            *(uint2*)(Xw + swz(yd * 256 + (16 * w + 4 * (lane >> 4)) * 2)) = pk;
        }
    }
    // leftover rows: copy row (l-1) -> row itOff per odd item (last chunk only)
    if (doLeft) {
        #pragma unroll
        for (int q = 0; q < 2; ++q) {
            int it = q * 32 + (tid >> 4);
            if (it < G) {
                int srow = (int)cpSk[it];
                if (srow != 0xFFFF) {
                    int ch = tid & 15;
                    uint4 v = *(const uint4*)(Xw + swz(srow * 256 + ch * 16));
                    *(uint4*)(Xw + swz((int)itOff[it] * 256 + ch * 16)) = v;
                }
            }
        }
    }
}

// ---------------------------------------------------------------------------
// Fused tree kernel v16 = round-13 v12 (64.9us, verified) with FPP 2->4:
// grid 256 = one rank-paired chain per block, Xw=352 rows, W1+W2 in regs
// (waves_per_eu(2,2) -> 256-reg budget), swapped GEMMs, 128-pair chunks.
// ---------------------------------------------------------------------------
__global__ void __launch_bounds__(512)
__attribute__((amdgpu_waves_per_eu(2, 2)))
tree_kernel(
    const float* __restrict__ args, const int4* __restrict__ chainTab,
    const ushort* __restrict__ W1p, const ushort* __restrict__ W2p,
    const float* __restrict__ b1, const float* __restrict__ b2,
    const float* __restrict__ lnw, const float* __restrict__ lnb,
    float* __restrict__ out)
{
    __shared__ __align__(16) char Xw[90112];        // 352 element rows x 256B
    __shared__ unsigned int schedAll[1536];         // 8 levels x 192 entries
    __shared__ float2 pbuf[1024];                   // LN partials [wave][pair]
    __shared__ ushort cpSAll[8][2];
    __shared__ ushort itOff[2], itL[2], itOut[2];
    __shared__ int itRow[2];
    __shared__ int nPAll[8];

    const int tid = threadIdx.x, lane = tid & 63, w = tid >> 6;

    // ---- one-time: W1 slice -> regs (wave w owns H cols 32w..32w+31)
    uint4 w1r[8][2];
    #pragma unroll
    for (int kk = 0; kk < 8; ++kk)
        #pragma unroll
        for (int n = 0; n < 2; ++n)
            w1r[kk][n] = *(const uint4*)(W1p + (size_t)(((kk * 16 + (w * 2 + n)) * 64 + lane) << 3));

    // ---- one-time: W2 slice -> regs (wave w owns Y cols 16w..16w+15)
    uint4 w2r[8];
    #pragma unroll
    for (int kk = 0; kk < 8; ++kk)
        w2r[kk] = *(const uint4*)(W2p + (size_t)(((kk * 8 + w) * 64 + lane) << 3));

    float bb1[2][4];
    #pragma unroll
    for (int n = 0; n < 2; ++n)
        #pragma unroll
        for (int i = 0; i < 4; ++i)
            bb1[n][i] = b1[32 * w + 16 * n + 4 * (lane >> 4) + i];
    float bb2v[4], lwv[4], lbv[4];
    #pragma unroll
    for (int i = 0; i < 4; ++i) {
        int c = 16 * w + 4 * (lane >> 4) + i;
        bb2v[i] = b2[c]; lwv[i] = lnw[c]; lbv[i] = lnb[c];
    }

    const int4 ct = chainTab[blockIdx.x];
    const int iA = ct.x & 0xFFFF, La = ct.x >> 16;
    const int iB = ct.y & 0xFFFF, Lb = ct.y >> 16;
    const int a0A = ct.z, a0B = ct.w;
    const int offBfull = (La + 1) & ~1;            // even-aligned B origin
    const bool split = (offBfull + Lb > 352);      // Xw capacity (rarely hit)
    const int npass = split ? 2 : 1;

    for (int pass = 0; pass < npass; ++pass) {
        int G, L0, r0, o0, off1 = 0, L1 = 0, r1 = 0, o1 = 0;
        if (!split)          { G = 2; L0 = La; r0 = a0A; o0 = iA; off1 = offBfull; L1 = Lb; r1 = a0B; o1 = iB; }
        else if (pass == 0)  { G = 1; L0 = La; r0 = a0A; o0 = iA; }
        else                 { G = 1; L0 = Lb; r0 = a0B; o0 = iB; }

        __syncthreads();   // previous pass's LDS readers done
        if (tid == 0) {
            itOff[0] = 0;            itL[0] = (ushort)L0; itRow[0] = r0; itOut[0] = (ushort)o0;
            itOff[1] = (ushort)off1; itL[1] = (ushort)L1; itRow[1] = r1; itOut[1] = (ushort)o1;
        }
        int nlev = (L0 > 1) ? (32 - __clz(L0 - 1)) : 0;
        if (G > 1 && L1 > 1) nlev = max(nlev, 32 - __clz(L1 - 1));

        // ---- phase A: wave0 builds all-level schedules (pure arithmetic);
        //      waves 1..7 stage leaves (pure arithmetic item test)
        if (w == 0) {
            int lA_ = L0, lB_ = (G > 1) ? L1 : 0;
            for (int k = 0; k < nlev; ++k) {
                int pA = lA_ >> 1, pB = lB_ >> 1, nPk = pA + pB;
                if (lane == 0) {
                    nPAll[k] = nPk;
                    cpSAll[k][0] = (lA_ > 1 && (lA_ & 1)) ? (ushort)(lA_ - 1) : (ushort)0xFFFF;
                    cpSAll[k][1] = (lB_ > 1 && (lB_ & 1)) ? (ushort)(off1 + lB_ - 1) : (ushort)0xFFFF;
                }
                #pragma unroll
                for (int rep = 0; rep < 3; ++rep) {
                    int e = lane + rep * 64;
                    unsigned entry = 0xFFFF0000u;
                    if (e < pA)
                        entry = (unsigned)e | ((unsigned)((lA_ & 1) + e) << 16);
                    else if (e < nPk) {
                        int j = e - pA;
                        entry = (unsigned)((off1 >> 1) + j) | ((unsigned)(off1 + (lB_ & 1) + j) << 16);
                    }
                    schedAll[k * 192 + e] = entry;
                }
                lA_ = pA + (lA_ & 1);
                lB_ = pB + (lB_ & 1);
            }
        } else {
            for (int job = tid - 64; job < 5632; job += 448) {
                int r = job >> 4, ch = job & 15;
                int src = -1;
                if (r < L0) src = r0 + r;
                else if (G > 1 && r >= off1 && r < off1 + L1) src = r1 + (r - off1);
                if (src >= 0) {
                    const float4 f0 = *(const float4*)(args + (size_t)src * D + ch * 8);
                    const float4 f1 = *(const float4*)(args + (size_t)src * D + ch * 8 + 4);
                    uint4 pk;
                    pk.x = (uint)f2b(f0.x) | ((uint)f2b(f0.y) << 16);
                    pk.y = (uint)f2b(f0.z) | ((uint)f2b(f0.w) << 16);
                    pk.z = (uint)f2b(f1.x) | ((uint)f2b(f1.y) << 16);
                    pk.w = (uint)f2b(f1.z) | ((uint)f2b(f1.w) << 16);
                    *(uint4*)(Xw + swz(r * 256 + ch * 16)) = pk;
                }
            }
        }
        __syncthreads();

        // ---- level loop; levels >128 pairs run in 128-pair chunks
        for (int k = 0; k < nlev; ++k) {
            const int nP = nPAll[k];
            if (nP == 0) break;
            int done = 0;
            while (done < nP) {
                const int chunk = min(nP - done, 128);
                const int nMf = (chunk + 15) >> 4;
                const bool last = (done + chunk >= nP);
                const unsigned* sk = schedAll + k * 192 + done;
                if (nMf > 4)
                    level_body<8>(Xw, sk, w1r, w2r, bb1, bb2v, lwv, lbv, pbuf, cpSAll[k], itOff, G, last, tid, lane, w);
                else if (nMf > 2)
                    level_body<4>(Xw, sk, w1r, w2r, bb1, bb2v, lwv, lbv, pbuf, cpSAll[k], itOff, G, last, tid, lane, w);
                else if (nMf == 2)
                    level_body<2>(Xw, sk, w1r, w2r, bb1, bb2v, lwv, lbv, pbuf, cpSAll[k], itOff, G, last, tid, lane, w);
                else
                    level_body<1>(Xw, sk, w1r, w2r, bb1, bb2v, lwv, lbv, pbuf, cpSAll[k], itOff, G, last, tid, lane, w);
                __syncthreads();
                done += chunk;
            }
        }

        // ---- output: root = live row itOff of each item; L==1 exact f32
        for (int j = tid; j < G * 32; j += 512) {
            int it = j >> 5, grp = j & 31;
            float4 o;
            if ((int)itL[it] == 1) {
                o = *(const float4*)(args + (size_t)itRow[it] * D + grp * 4);
            } else {
                uint2 v = *(const uint2*)(Xw + swz((int)itOff[it] * 256 + grp * 8));
                o.x = b2f((ushort)(v.x & 0xFFFFu));
                o.y = b2f((ushort)(v.x >> 16));
                o.z = b2f((ushort)(v.y & 0xFFFFu));
                o.w = b2f((ushort)(v.y >> 16));
            }
            *(float4*)(out + (size_t)itOut[it] * D + grp * 4) = o;
        }
    }
}

// ---------------------------------------------------------------------------
extern "C" void kernel_launch(void* const* d_in, const int* in_sizes, int n_in,
                              void* d_out, int out_size, void* d_ws, size_t ws_size,
                              hipStream_t stream) {
    const float* args   = (const float*)d_in[0];
    const int*   limits = (const int*)d_in[1];     // harness: integer -> const int*
    const float* W1     = (const float*)d_in[2];
    const float* b1     = (const float*)d_in[3];
    const float* W2     = (const float*)d_in[4];
    const float* b2     = (const float*)d_in[5];
    const float* lnw    = (const float*)d_in[6];
    const float* lnb    = (const float*)d_in[7];

    char* ws = (char*)d_ws;
    ushort* W1p      = (ushort*)(ws);              // 131072 B
    ushort* W2p      = (ushort*)(ws + 131072);     //  65536 B
    int4*   chainTab = (int4*)  (ws + 196608);     //   4096 B

    prep_kernel<<<193, 512, 0, stream>>>(W1, W2, limits, W1p, W2p, chainTab);
    tree_kernel<<<256, 512, 0, stream>>>(args, chainTab, W1p, W2p, b1, b2, lnw, lnb,
                                         (float*)d_out);
}